// Round 3
// baseline (259.797 us; speedup 1.0000x reference)
//
#include <hip/hip_runtime.h>

#define NPAIR 96
#define MAXB 64
#define CAP 256

__constant__ float c_anc[9][2] = {
    {116.f, 90.f}, {156.f, 198.f}, {373.f, 326.f},
    { 30.f, 61.f}, { 62.f, 45.f}, { 59.f, 119.f},
    { 10.f, 13.f}, { 16.f, 30.f}, { 33.f, 23.f}};

typedef float floatx4 __attribute__((ext_vector_type(4), aligned(4)));

__device__ __forceinline__ float sigm(float x) { return 1.f / (1.f + expf(-x)); }

// bce_logits(t, x) = max(x,0) - x*t + log1p(exp(-|x|))
__device__ __forceinline__ float bce_f(float t, float x) {
    return fmaxf(x, 0.f) - x * t + logf(1.f + expf(-fabsf(x)));
}

// block j (0..41 within a batch) -> layer l, chunk blk, grid S
__device__ __forceinline__ void map_block(int j, int& l, int& blk, int& S) {
    if (j < 2)       { l = 0; blk = j;      S = 13; }
    else if (j < 10) { l = 1; blk = j - 2;  S = 26; }
    else             { l = 2; blk = j - 10; S = 52; }
}

template <int ITERS>
__device__ __forceinline__ void scan_obj(const float* __restrict__ ybase,
                                         int nCells, int tid,
                                         unsigned long long* swords) {
    float ov[ITERS];
#pragma unroll
    for (int k = 0; k < ITERS; ++k) {
        int c = tid + (k << 8);
        ov[k] = (c < nCells) ? ybase[(long long)c * 85] : 0.f;
    }
    int lane = tid & 63, wv = tid >> 6;
#pragma unroll
    for (int k = 0; k < ITERS; ++k) {
        unsigned long long m = __ballot(ov[k] > 0.5f);
        if (lane == 0) swords[k * 4 + wv] = m;
    }
}

// One block per (batch, layer): bitmap + ordered box list + positive losses.
// Also zeroes d_out (pair 0) and writes posloss[pair] for neg_k to fold in.
__global__ __launch_bounds__(256) void prep_k(
    const float* __restrict__ yt,
    const float* __restrict__ p13, const float* __restrict__ p26,
    const float* __restrict__ p52,
    float4* __restrict__ oboxes, int* __restrict__ counts,
    unsigned long long* __restrict__ bmp_all,
    float* __restrict__ posloss, float* __restrict__ out)
{
    int pair = blockIdx.x;
    int tid = threadIdx.x;
    int b = pair / 3;
    int l = pair - b * 3;
    int S      = (l == 0) ? 13  : (l == 1) ? 26  : 52;
    int n0     = (l == 0) ? 0   : (l == 1) ? 169 : 845;
    int nwords = (l == 0) ? 8   : (l == 1) ? 32  : 128;
    int nCells = S * S * 3;
    float Sf = (float)S;
    const float* ybase = yt + (long long)(b * 3549 + n0) * 255;
    const float* pred  = (l == 0) ? p13 : (l == 1) ? p26 : p52;
    const float* pbase = pred + (long long)b * S * S * 255;

    if (pair == 0 && tid < 32) out[tid] = 0.f;

    __shared__ unsigned long long swords[128];
    __shared__ int sidx[CAP];
    __shared__ int sbase[2];
    __shared__ int stot_s;
    __shared__ float pls[4];

    if (l == 0)      scan_obj<2 >(ybase, nCells, tid, swords);
    else if (l == 1) scan_obj<8 >(ybase, nCells, tid, swords);
    else             scan_obj<32>(ybase, nCells, tid, swords);
    __syncthreads();

    int lane = tid & 63, wv = tid >> 6;
    // exclusive prefix over word popcounts (log-step shfl scan, waves 0/1)
    unsigned long long w = 0ULL;
    int pc = 0;
    if (tid < 128) {
        w = (tid < nwords) ? swords[tid] : 0ULL;
        pc = __popcll(w);
    }
    int x = pc;
#pragma unroll
    for (int d = 1; d < 64; d <<= 1) {
        int y = __shfl_up(x, d, 64);
        if (lane >= d) x += y;
    }
    if (tid < 128 && lane == 63) sbase[wv] = x;
    if (tid < nwords) bmp_all[(long long)pair * 128 + tid] = w;
    __syncthreads();
    if (tid == 0) stot_s = sbase[0] + sbase[1];
    if (tid < 128) {
        int base = x - pc + (wv ? sbase[0] : 0);
        unsigned long long ww = w;
        while (ww) {
            int bit = __ffsll((long long)ww) - 1;
            if (base < CAP) sidx[base] = tid * 64 + bit;
            ++base;
            ww &= ww - 1;
        }
    }
    __syncthreads();

    int stot = stot_s;
    int TC = stot < CAP ? stot : CAP;
    int MB = TC < MAXB ? TC : MAXB;
    if (tid == 0) counts[pair] = MB;
    if (tid < MB) {
        int idx = sidx[tid];
        const float* yc = ybase + (long long)idx * 85;
        oboxes[pair * MAXB + tid] = make_float4(yc[1], yc[2], yc[3], yc[4]);
    }

    // positive losses: wave i handles positives i, i+4, ... ; 80 cls channels
    // spread across 64 lanes (coalesced); lane 0 adds the 5 box/conf terms.
    float wsum = 0.f;
    for (int i = wv; i < TC; i += 4) {
        int idx = sidx[i];
        const float* yc = ybase + (long long)idx * 85;
        const float* pc_ = pbase + (long long)idx * 85;
        float part = bce_f(yc[5 + lane], sigm(pc_[5 + lane]));
        if (lane < 16)
            part += bce_f(yc[69 + lane], sigm(pc_[69 + lane]));
        if (lane == 0) {
            int p_ = idx / 3, a = idx - p_ * 3;
            int gh = p_ / S, gw = p_ - gh * S;
            float aw = c_anc[l * 3 + a][0], ah = c_anc[l * 3 + a][1];
            float v0 = pc_[0], v1 = pc_[1], v2 = pc_[2], v3 = pc_[3], v4 = pc_[4];
            float t1 = yc[1], t2 = yc[2], t3 = yc[3], t4 = yc[4];
            part += bce_f(1.f, sigm(v0));
            float sc = 2.f - t3 * t4;
            float px = (sigm(v1) + (float)gw) / Sf;
            float py = (sigm(v2) + (float)gh) / Sf;
            part += sc * (bce_f(t1 * Sf - (float)gw, px) +
                          bce_f(t2 * Sf - (float)gh, py));
            float pw = expf(v3) * aw / Sf, ph = expf(v4) * ah / Sf;
            float twx = logf(t3 / aw * 416.f), twy = logf(t4 / ah * 416.f);
            part += sc * 0.5f * ((twx - pw) * (twx - pw) + (twy - ph) * (twy - ph));
        }
#pragma unroll
        for (int off = 32; off > 0; off >>= 1)
            part += __shfl_down(part, off, 64);
        if (lane == 0) wsum += part;
    }
    if (lane == 0) pls[wv] = wsum;
    __syncthreads();
    if (tid == 0) posloss[pair] = pls[0] + pls[1] + pls[2] + pls[3];
}

// ---------------- negatives: conf loss with IoU-ignore (1344 blocks) --------
__global__ __launch_bounds__(256) void neg_k(
    const float* __restrict__ p13, const float* __restrict__ p26,
    const float* __restrict__ p52,
    const float4* __restrict__ oboxes, const int* __restrict__ counts,
    const unsigned long long* __restrict__ bmp_all,
    const float* __restrict__ posloss, float* __restrict__ out)
{
    int bid = blockIdx.x;
    int tid = threadIdx.x;
    int b = bid / 42;
    int j = bid - b * 42;
    int l, blk, S;
    map_block(j, l, blk, S);
    int nCells = S * S * 3;
    int pair = b * 3 + l;
    float Sf = (float)S;
    const float* pred  = (l == 0) ? p13 : (l == 1) ? p26 : p52;
    const float* pbase = pred + (long long)b * S * S * 255;

    __shared__ float sxmin[MAXB], sxmax[MAXB], symin[MAXB], symax[MAXB], sba[MAXB];
    int count = counts[pair];
    if (tid < count) {
        float4 g = oboxes[pair * MAXB + tid];
        sxmin[tid] = g.x - g.z * 0.5f;
        sxmax[tid] = g.x + g.z * 0.5f;
        symin[tid] = g.y - g.w * 0.5f;
        symax[tid] = g.y + g.w * 0.5f;
        sba[tid]   = g.z * g.w;
    }
    __syncthreads();

    float loss = 0.f;
    int c = blk * 256 + tid;
    if (c < nCells) {
        unsigned long long word = bmp_all[(long long)pair * 128 + (c >> 6)];
        if (!((word >> (c & 63)) & 1ULL)) {
            const float* pc = pbase + (long long)c * 85;
            floatx4 v03 = *(const floatx4*)pc;   // dwordx4, 4B-aligned ok on gfx950
            float v0 = v03.x;
            if (count == 0) {
                loss = bce_f(0.f, sigm(v0));
            } else {
                float v4 = pc[4];
                int p_ = c / 3, a = c - p_ * 3;
                int gh = p_ / S, gw = p_ - gh * S;
                float aw = c_anc[l * 3 + a][0], ah = c_anc[l * 3 + a][1];
                float px = (sigm(v03.y) + (float)gw) / Sf;
                float py = (sigm(v03.z) + (float)gh) / Sf;
                float pw = expf(v03.w) * aw / Sf, ph = expf(v4) * ah / Sf;
                float pxmin = px - pw * 0.5f, pxmax = px + pw * 0.5f;
                float pymin = py - ph * 0.5f, pymax = py + ph * 0.5f;
                float parea = pw * ph;
                bool hit = false;
                // iou >= 0.5 <=> 2*inter >= pa+ba-inter <=> 3*inter >= pa+ba
#pragma unroll 4
                for (int i = 0; i < count; ++i) {
                    float iw = fminf(pxmax, sxmax[i]) - fmaxf(pxmin, sxmin[i]);
                    float ih = fminf(pymax, symax[i]) - fmaxf(pymin, symin[i]);
                    float inter = fmaxf(iw, 0.f) * fmaxf(ih, 0.f);
                    hit = hit || (3.f * inter >= parea + sba[i]);
                }
                if (!hit) loss = bce_f(0.f, sigm(v0));
            }
        }
    }
    if (tid == 0 && blk == 0) loss += posloss[pair];

#pragma unroll
    for (int off = 32; off > 0; off >>= 1)
        loss += __shfl_down(loss, off, 64);
    __shared__ float wsum[4];
    if ((tid & 63) == 0) wsum[tid >> 6] = loss;
    __syncthreads();
    if (tid == 0)
        atomicAdd(out + b, wsum[0] + wsum[1] + wsum[2] + wsum[3]);
}

extern "C" void kernel_launch(void* const* d_in, const int* in_sizes, int n_in,
                              void* d_out, int out_size, void* d_ws, size_t ws_size,
                              hipStream_t stream) {
    (void)in_sizes; (void)n_in; (void)out_size; (void)ws_size;
    const float* yt  = (const float*)d_in[0];
    const float* p13 = (const float*)d_in[1];
    const float* p26 = (const float*)d_in[2];
    const float* p52 = (const float*)d_in[3];
    float* out = (float*)d_out;

    // ws: bitmap[96][128] u64 | oboxes[96][64] float4 | counts[96] | posloss[96]
    unsigned long long* bmp = (unsigned long long*)d_ws;
    float4* oboxes = (float4*)((char*)d_ws + NPAIR * 128 * 8);
    int* counts    = (int*)((char*)d_ws + NPAIR * 128 * 8 + NPAIR * MAXB * 16);
    float* posloss = (float*)((char*)d_ws + NPAIR * 128 * 8 + NPAIR * MAXB * 16
                              + NPAIR * sizeof(int));

    prep_k<<<NPAIR, 256, 0, stream>>>(yt, p13, p26, p52, oboxes, counts, bmp,
                                      posloss, out);
    neg_k<<<32 * 42, 256, 0, stream>>>(p13, p26, p52, oboxes, counts, bmp,
                                       posloss, out);
}